// Round 7
// baseline (115.065 us; speedup 1.0000x reference)
//
#include <hip/hip_runtime.h>

#define N_NODES 2048
#define F_IN    2048
#define G1      10
#define NCLS    10
#define NEDGE   65536
#define JCHUNKS 32
#define JPER    64                   // K-elements per chunk (two 32-col LDS passes)
#define HSLICES 128                  // histogram edge slices (fused into k_gemm)
#define ZSLICES 64                   // scatter edge slices per k-half

// Device-global intermediates (bss of the .so) — fully overwritten each call.
__device__ float g_p[JCHUNKS * 20 * N_NODES];       // [jc][k][row] split-K partials (5.25 MB)
__device__ int   g_degp[HSLICES * N_NODES];         // per-slice degree histograms (1 MB)
__device__ float g_dis[N_NODES];                    // deg>0 ? rsqrt(deg) : 0
__device__ float g_y[N_NODES * 20];                 // [row][k]: k<10 x@W0, k>=10 x@W1
__device__ float g_zp[2 * ZSLICES * N_NODES * 5];   // [khalf][slice][i*5+kk] (5.25 MB)

// ---- 1) split-K GEMM (LDS-staged coalesced x, 2 passes) + fused histogram ----
// Grid (32,8). Per pass: 256 rows x 32 cols staged, LDS stride 33 (2 lanes/bank
// = free). j loop-uniform -> W rows via s_load broadcast. Blocks with by<4 then
// redo the degree histogram (slice = by*32+jc), reusing the x-tile LDS.
__global__ __launch_bounds__(256) void k_gemm(const float* __restrict__ x,
                                              const float* __restrict__ W0,
                                              const float* __restrict__ W1,
                                              const int* __restrict__ ei) {
    __shared__ float sx[256 * 33];   // 33.8 KB
    int jc      = blockIdx.x;        // 0..31
    int rowbase = blockIdx.y * 256;

    float acc[20];
    #pragma unroll
    for (int k = 0; k < 20; ++k) acc[k] = 0.f;

    #pragma unroll
    for (int half = 0; half < 2; ++half) {
        int j0 = jc * JPER + half * 32;
        if (half) __syncthreads();               // all reads of pass 0 done
        #pragma unroll
        for (int rep = 0; rep < 8; ++rep) {
            int idx = rep * 256 + threadIdx.x;
            int r = idx >> 3, c4 = idx & 7;
            float4 v = *(const float4*)(x + (size_t)(rowbase + r) * F_IN + j0 + c4 * 4);
            float* d = sx + r * 33 + c4 * 4;
            d[0] = v.x; d[1] = v.y; d[2] = v.z; d[3] = v.w;
        }
        __syncthreads();
        const float* xr = sx + threadIdx.x * 33;
        #pragma unroll
        for (int j = 0; j < 32; ++j) {
            float xu = xr[j];
            const float* w0r = W0 + (size_t)(j0 + j) * G1;  // uniform -> s_load
            const float* w1r = W1 + (size_t)(j0 + j) * G1;
            #pragma unroll
            for (int k = 0; k < G1; ++k) {
                acc[k]      += xu * w0r[k];
                acc[10 + k] += xu * w1r[k];
            }
        }
    }
    int row = rowbase + threadIdx.x;
    #pragma unroll
    for (int k = 0; k < 20; ++k)
        g_p[((size_t)jc * 20 + k) * N_NODES + row] = acc[k];   // coalesced

    // fused degree histogram: 128 of 256 blocks, 512 edges each
    if (blockIdx.y < 4) {
        int slice = blockIdx.y * 32 + jc;        // 0..127
        __syncthreads();
        int* h = (int*)sx;
        for (int t = threadIdx.x; t < N_NODES; t += 256) h[t] = 0;
        __syncthreads();
        int base = slice * (NEDGE / HSLICES);    // 512 edges per slice
        #pragma unroll
        for (int u = 0; u < 2; ++u)
            atomicAdd(&h[ei[base + u * 256 + threadIdx.x]], 1);
        __syncthreads();
        for (int t = threadIdx.x; t < N_NODES; t += 256)
            g_degp[slice * N_NODES + t] = h[t];
    }
}

// ---- 2) reduce GEMM partials -> g_y ; degree partials -> g_dis ----
__global__ __launch_bounds__(256) void k_reduce() {
    int t   = blockIdx.x * 256 + threadIdx.x;   // 160 blocks -> t < 40960
    int k   = t >> 11;
    int row = t & (N_NODES - 1);
    float s = 0.f;
    #pragma unroll 16
    for (int jc = 0; jc < JCHUNKS; ++jc)
        s += g_p[((size_t)jc * 20 + k) * N_NODES + row];
    g_y[row * 20 + k] = s;
    if (t < N_NODES) {
        int d = 0;
        #pragma unroll 16
        for (int sl = 0; sl < HSLICES; ++sl) d += g_degp[sl * N_NODES + t];
        g_dis[t] = (d > 0) ? rsqrtf((float)d) : 0.f;
    }
}

// ---- 3) edge scatter in projected space, LDS-privatized ----
// 128 blocks: khalf = bx>>6 (k in [khalf*5,khalf*5+5)), slice = bx&63 (1024 edges).
__global__ __launch_bounds__(256) void k_scatter(const int* __restrict__ ei) {
    __shared__ float zl[N_NODES * 5];            // 40 KB
    int khalf  = blockIdx.x >> 6;
    int bslice = blockIdx.x & (ZSLICES - 1);
    float4* zl4 = (float4*)zl;
    #pragma unroll
    for (int t = threadIdx.x; t < N_NODES * 5 / 4; t += 256)
        zl4[t] = make_float4(0.f, 0.f, 0.f, 0.f);
    __syncthreads();
    int base = bslice * (NEDGE / ZSLICES);
    #pragma unroll
    for (int u = 0; u < NEDGE / ZSLICES / 256; ++u) {
        int e = base + u * 256 + threadIdx.x;
        int r = ei[e], c = ei[NEDGE + e];
        float w = -g_dis[r] * g_dis[c];          // 0 if either deg==0
        const float* y1 = g_y + r * 20 + 10 + khalf * 5;
        float* zz = zl + c * 5;
        #pragma unroll
        for (int kk = 0; kk < 5; ++kk) atomicAdd(&zz[kk], w * y1[kk]);
    }
    __syncthreads();
    float4* dst = (float4*)(g_zp + ((size_t)khalf * ZSLICES + bslice) * (N_NODES * 5));
    #pragma unroll
    for (int t = threadIdx.x; t < N_NODES * 5 / 4; t += 256) dst[t] = zl4[t];
}

// ---- 4) fused z-reduction + epilogue, 64 blocks x 32 nodes ----
// zred is a pure slice-sum, so each block reduces z for its own nodes into LDS
// then runs relu(y0+z+b) @ Wf + log_softmax for them. No g_z round-trip.
__global__ __launch_bounds__(256) void k_zf(const float* __restrict__ b,
                                            const float* __restrict__ Wf,
                                            const float* __restrict__ bfv,
                                            float* __restrict__ out) {
    __shared__ float zb[320];                    // [il][k] for 32 nodes
    int nb = blockIdx.x * 32;
    // v = khalf*160 + il*5 + kk  -> lanes 0..159 read khalf0 contiguously
    for (int v = threadIdx.x; v < 320; v += 256) {
        int khalf = v / 160;
        int rem   = v - khalf * 160;             // il*5 + kk
        int il    = rem / 5, kk = rem - il * 5;
        float s = 0.f;
        #pragma unroll 16
        for (int sl = 0; sl < ZSLICES; ++sl)
            s += g_zp[((size_t)khalf * ZSLICES + sl) * (N_NODES * 5) + (nb + il) * 5 + kk];
        zb[il * 10 + khalf * 5 + kk] = s;
    }
    __syncthreads();
    if (threadIdx.x < 32) {
        int i = nb + threadIdx.x;
        float h[G1];
        #pragma unroll
        for (int k = 0; k < G1; ++k)
            h[k] = fmaxf(g_y[i * 20 + k] + zb[threadIdx.x * 10 + k] + b[k], 0.f);
        float lo[NCLS];
        #pragma unroll
        for (int c = 0; c < NCLS; ++c) lo[c] = bfv[c];
        #pragma unroll
        for (int k = 0; k < G1; ++k) {
            float hk = h[k];
            #pragma unroll
            for (int c = 0; c < NCLS; ++c) lo[c] += hk * Wf[k * NCLS + c];
        }
        float m = lo[0];
        #pragma unroll
        for (int c = 1; c < NCLS; ++c) m = fmaxf(m, lo[c]);
        float s = 0.f;
        #pragma unroll
        for (int c = 0; c < NCLS; ++c) s += expf(lo[c] - m);
        float ls = logf(s);
        #pragma unroll
        for (int c = 0; c < NCLS; ++c) out[i * NCLS + c] = lo[c] - m - ls;
    }
}

extern "C" void kernel_launch(void* const* d_in, const int* in_sizes, int n_in,
                              void* d_out, int out_size, void* d_ws, size_t ws_size,
                              hipStream_t stream) {
    const float* x   = (const float*)d_in[0];
    const int*   ei  = (const int*)d_in[1];
    const float* W0  = (const float*)d_in[2];
    const float* W1  = (const float*)d_in[3];
    const float* b   = (const float*)d_in[4];
    const float* Wf  = (const float*)d_in[5];
    const float* bfv = (const float*)d_in[6];
    float* out = (float*)d_out;

    k_gemm<<<dim3(JCHUNKS, N_NODES / 256), 256, 0, stream>>>(x, W0, W1, ei);
    k_reduce<<<(N_NODES * 20) / 256, 256, 0, stream>>>();
    k_scatter<<<2 * ZSLICES, 256, 0, stream>>>(ei);
    k_zf<<<N_NODES / 32, 256, 0, stream>>>(b, Wf, bfv, out);
}

// Round 8
// 112.056 us; speedup vs baseline: 1.0269x; 1.0269x over previous
//
#include <hip/hip_runtime.h>

#define N_NODES 2048
#define F_IN    2048
#define G1      10
#define NCLS    10
#define NEDGE   65536
#define JCHUNKS 64
#define JPER    32                   // K-elements per chunk (single LDS pass)
#define HSLICES 128                  // histogram edge slices (fused into k_gemm)
#define ZSLICES 64                   // scatter edge slices per k-half

// Device-global intermediates (bss of the .so) — fully overwritten each call.
__device__ float g_p[JCHUNKS * 20 * N_NODES];       // [jc][k][row] split-K partials (10.5 MB)
__device__ int   g_degp[HSLICES * N_NODES];         // per-slice degree histograms (1 MB)
__device__ float g_dis[N_NODES];                    // deg>0 ? rsqrt(deg) : 0
__device__ float g_y[N_NODES * 20];                 // [row][k]: k<10 x@W0, k>=10 x@W1
__device__ float g_zp[2 * ZSLICES * N_NODES * 5];   // [khalf][slice][i*5+kk] (5.25 MB)

// ---- 1) split-K GEMM (LDS-staged coalesced x) + fused degree histogram ----
// Grid (64,8) = 512 blocks = 2/CU (syncthreads stalls hidden by co-resident
// block). Tile 256 rows x 32 cols, LDS stride 33 -> 2 lanes/bank (free).
// j loop-uniform -> W rows via s_load broadcast. by<4 && jc<32 blocks then
// redo the degree histogram (slice = by*32+jc), reusing the x-tile LDS.
__global__ __launch_bounds__(256) void k_gemm(const float* __restrict__ x,
                                              const float* __restrict__ W0,
                                              const float* __restrict__ W1,
                                              const int* __restrict__ ei) {
    __shared__ float sx[256 * 33];   // 33.8 KB
    int jc      = blockIdx.x;        // 0..63
    int rowbase = blockIdx.y * 256;
    int j0      = jc * JPER;

    #pragma unroll
    for (int rep = 0; rep < 8; ++rep) {
        int idx = rep * 256 + threadIdx.x;
        int r = idx >> 3, c4 = idx & 7;
        float4 v = *(const float4*)(x + (size_t)(rowbase + r) * F_IN + j0 + c4 * 4);
        float* d = sx + r * 33 + c4 * 4;
        d[0] = v.x; d[1] = v.y; d[2] = v.z; d[3] = v.w;
    }
    __syncthreads();

    float acc[20];
    #pragma unroll
    for (int k = 0; k < 20; ++k) acc[k] = 0.f;

    const float* xr = sx + threadIdx.x * 33;
    #pragma unroll
    for (int j = 0; j < JPER; ++j) {
        float xu = xr[j];
        const float* w0r = W0 + (size_t)(j0 + j) * G1;  // uniform -> s_load
        const float* w1r = W1 + (size_t)(j0 + j) * G1;
        #pragma unroll
        for (int k = 0; k < G1; ++k) {
            acc[k]      += xu * w0r[k];
            acc[10 + k] += xu * w1r[k];
        }
    }
    int row = rowbase + threadIdx.x;
    #pragma unroll
    for (int k = 0; k < 20; ++k)
        g_p[((size_t)jc * 20 + k) * N_NODES + row] = acc[k];   // coalesced

    // fused degree histogram: 128 of 512 blocks, 512 edges each
    if (blockIdx.y < 4 && jc < 32) {
        int slice = blockIdx.y * 32 + jc;        // 0..127
        __syncthreads();
        int* h = (int*)sx;
        for (int t = threadIdx.x; t < N_NODES; t += 256) h[t] = 0;
        __syncthreads();
        int base = slice * (NEDGE / HSLICES);    // 512 edges per slice
        #pragma unroll
        for (int u = 0; u < 2; ++u)
            atomicAdd(&h[ei[base + u * 256 + threadIdx.x]], 1);
        __syncthreads();
        for (int t = threadIdx.x; t < N_NODES; t += 256)
            g_degp[slice * N_NODES + t] = h[t];
    }
}

// ---- 2) reduce GEMM partials -> g_y ; degree partials -> g_dis ----
__global__ __launch_bounds__(256) void k_reduce() {
    int t   = blockIdx.x * 256 + threadIdx.x;   // 160 blocks -> t < 40960
    int k   = t >> 11;
    int row = t & (N_NODES - 1);
    float s = 0.f;
    #pragma unroll 16
    for (int jc = 0; jc < JCHUNKS; ++jc)
        s += g_p[((size_t)jc * 20 + k) * N_NODES + row];
    g_y[row * 20 + k] = s;
    if (t < N_NODES) {
        int d = 0;
        #pragma unroll 16
        for (int sl = 0; sl < HSLICES; ++sl) d += g_degp[sl * N_NODES + t];
        g_dis[t] = (d > 0) ? rsqrtf((float)d) : 0.f;
    }
}

// ---- 3) edge scatter in projected space, LDS-privatized ----
// 128 blocks: khalf = bx>>6 (k in [khalf*5,khalf*5+5)), slice = bx&63 (1024 edges).
__global__ __launch_bounds__(256) void k_scatter(const int* __restrict__ ei) {
    __shared__ float zl[N_NODES * 5];            // 40 KB
    int khalf  = blockIdx.x >> 6;
    int bslice = blockIdx.x & (ZSLICES - 1);
    float4* zl4 = (float4*)zl;
    #pragma unroll
    for (int t = threadIdx.x; t < N_NODES * 5 / 4; t += 256)
        zl4[t] = make_float4(0.f, 0.f, 0.f, 0.f);
    __syncthreads();
    int base = bslice * (NEDGE / ZSLICES);
    #pragma unroll
    for (int u = 0; u < NEDGE / ZSLICES / 256; ++u) {
        int e = base + u * 256 + threadIdx.x;
        int r = ei[e], c = ei[NEDGE + e];
        float w = -g_dis[r] * g_dis[c];          // 0 if either deg==0
        const float* y1 = g_y + r * 20 + 10 + khalf * 5;
        float* zz = zl + c * 5;
        #pragma unroll
        for (int kk = 0; kk < 5; ++kk) atomicAdd(&zz[kk], w * y1[kk]);
    }
    __syncthreads();
    float4* dst = (float4*)(g_zp + ((size_t)khalf * ZSLICES + bslice) * (N_NODES * 5));
    #pragma unroll
    for (int t = threadIdx.x; t < N_NODES * 5 / 4; t += 256) dst[t] = zl4[t];
}

// ---- 4) fused z-reduction + epilogue, 64 blocks x 32 nodes ----
// z for a node is a pure slice-sum: each block reduces z for its 32 nodes into
// LDS then runs relu(y0+z+b) @ Wf + log_softmax. No g_z round-trip.
__global__ __launch_bounds__(256) void k_zf(const float* __restrict__ b,
                                            const float* __restrict__ Wf,
                                            const float* __restrict__ bfv,
                                            float* __restrict__ out) {
    __shared__ float zb[320];                    // [il][k] for 32 nodes
    int nb = blockIdx.x * 32;
    for (int v = threadIdx.x; v < 320; v += 256) {
        int khalf = v / 160;
        int rem   = v - khalf * 160;             // il*5 + kk
        int il    = rem / 5, kk = rem - il * 5;
        float s = 0.f;
        #pragma unroll 16
        for (int sl = 0; sl < ZSLICES; ++sl)
            s += g_zp[((size_t)khalf * ZSLICES + sl) * (N_NODES * 5) + (nb + il) * 5 + kk];
        zb[il * 10 + khalf * 5 + kk] = s;
    }
    __syncthreads();
    if (threadIdx.x < 32) {
        int i = nb + threadIdx.x;
        float h[G1];
        #pragma unroll
        for (int k = 0; k < G1; ++k)
            h[k] = fmaxf(g_y[i * 20 + k] + zb[threadIdx.x * 10 + k] + b[k], 0.f);
        float lo[NCLS];
        #pragma unroll
        for (int c = 0; c < NCLS; ++c) lo[c] = bfv[c];
        #pragma unroll
        for (int k = 0; k < G1; ++k) {
            float hk = h[k];
            #pragma unroll
            for (int c = 0; c < NCLS; ++c) lo[c] += hk * Wf[k * NCLS + c];
        }
        float m = lo[0];
        #pragma unroll
        for (int c = 1; c < NCLS; ++c) m = fmaxf(m, lo[c]);
        float s = 0.f;
        #pragma unroll
        for (int c = 0; c < NCLS; ++c) s += expf(lo[c] - m);
        float ls = logf(s);
        #pragma unroll
        for (int c = 0; c < NCLS; ++c) out[i * NCLS + c] = lo[c] - m - ls;
    }
}

extern "C" void kernel_launch(void* const* d_in, const int* in_sizes, int n_in,
                              void* d_out, int out_size, void* d_ws, size_t ws_size,
                              hipStream_t stream) {
    const float* x   = (const float*)d_in[0];
    const int*   ei  = (const int*)d_in[1];
    const float* W0  = (const float*)d_in[2];
    const float* W1  = (const float*)d_in[3];
    const float* b   = (const float*)d_in[4];
    const float* Wf  = (const float*)d_in[5];
    const float* bfv = (const float*)d_in[6];
    float* out = (float*)d_out;

    k_gemm<<<dim3(JCHUNKS, N_NODES / 256), 256, 0, stream>>>(x, W0, W1, ei);
    k_reduce<<<(N_NODES * 20) / 256, 256, 0, stream>>>();
    k_scatter<<<2 * ZSLICES, 256, 0, stream>>>(ei);
    k_zf<<<N_NODES / 32, 256, 0, stream>>>(b, Wf, bfv, out);
}